// Round 5
// baseline (101.295 us; speedup 1.0000x reference)
//
#include <hip/hip_runtime.h>
#include <math.h>

#define SEQ   32768
#define DENC  200
#define NH    8192

#define K1B    256
#define K1ROWS (NH / K1B)      // 32 W-rows per K1 block
#define K2B    1024
#define K2ROWS (SEQ / K2B)     // 32 enc rows per K2 block
#define RPW    8               // rows per wave (4 waves/block)

// ws layout in u64 units:
#define WS_VACC   0                      // 4 banks x 200 doubles = 800
#define WS_K1CNT  800                    // u64 arrival counter (own line)
#define WS_SUBT(i)  (816 + 16*(i))       // 8 double sum slots, 128B apart
#define WS_ROOT2  944                    // u64 root counter
#define WS_SUB2(i)  (960 + 16*(i))       // 8 u64 sub-counters
#define WS_GO2(i)   (1088 + 16*(i))      // 8 u64 go flags (payload = total bits)
#define WS_VFIN   1216                   // float[200] final v
#define WS_ZERO_BYTES (1216 * 8)

__device__ __forceinline__ float wave_sum(float x) {
    #pragma unroll
    for (int off = 32; off; off >>= 1) x += __shfl_xor(x, off, 64);
    return x;
}

// ---- K1: v[d] = sum_h W[h][d]*hidden[h] via f64 atomic banks; last block
// finalizes to float. (bias term skipped: constant shift cancels in softmax.)
__global__ __launch_bounds__(256) void k1_proj(const float* __restrict__ W,
                                               const float* __restrict__ hidden,
                                               unsigned long long* __restrict__ ws) {
    double* vacc = (double*)(ws + WS_VACC);
    float*  vfin = (float*)(ws + WS_VFIN);
    __shared__ int last;
    const int t = threadIdx.x, b = blockIdx.x;
    const int h0 = b * K1ROWS;

    if (t < DENC) {
        float acc = 0.f;
        #pragma unroll 8
        for (int i = 0; i < K1ROWS; ++i)
            acc = fmaf(W[(size_t)(h0 + i) * DENC + t], hidden[h0 + i], acc);
        unsafeAtomicAdd(&vacc[(b & 3) * DENC + t], (double)acc);
    }
    __syncthreads();   // drains vmcnt for every wave -> block's atomics complete
    if (t == 0)
        last = (atomicAdd(&ws[WS_K1CNT], 1ull) == (unsigned long long)(K1B - 1));
    __syncthreads();
    if (last && t < DENC) {
        double v = 0.0;
        #pragma unroll
        for (int k = 0; k < 4; ++k)
            v += __hip_atomic_load(&vacc[k * DENC + t], __ATOMIC_RELAXED,
                                   __HIP_MEMORY_SCOPE_AGENT);
        vfin[t] = (float)v;   // plain store: next kernel boundary makes it coherent
    }
}

// ---- K2: energies from registers, exp via exp2f + exponent-bit double scale,
// global sum via spread f64 atomics + single read-poll barrier, normalize.
__global__ __launch_bounds__(256, 4) void k2_attn(const float* __restrict__ enc,
                                                  unsigned long long* __restrict__ ws,
                                                  float* __restrict__ out) {
    const float* vfin = (const float*)(ws + WS_VFIN);
    __shared__ float  v_lds[DENC];
    __shared__ double s_lds[4];
    __shared__ double inv_lds;
    const int t = threadIdx.x, b = blockIdx.x;
    const int lane = t & 63, wid = t >> 6;

    if (t < DENC) v_lds[t] = vfin[t];
    __syncthreads();

    const bool act = (lane < 50);
    float4 v4 = make_float4(0.f, 0.f, 0.f, 0.f);
    if (act) v4 = *(const float4*)(v_lds + lane * 4);

    const int s0 = b * K2ROWS + wid * RPW;
    const float* ebase = enc + (size_t)s0 * DENC + lane * 4;

    float4 q0,q1,q2,q3,q4,q5,q6,q7;
    q0 = *(const float4*)(act ? ebase + 0*DENC : enc);
    q1 = *(const float4*)(act ? ebase + 1*DENC : enc);
    q2 = *(const float4*)(act ? ebase + 2*DENC : enc);
    q3 = *(const float4*)(act ? ebase + 3*DENC : enc);
    q4 = *(const float4*)(act ? ebase + 4*DENC : enc);
    q5 = *(const float4*)(act ? ebase + 5*DENC : enc);
    q6 = *(const float4*)(act ? ebase + 6*DENC : enc);
    q7 = *(const float4*)(act ? ebase + 7*DENC : enc);

    float e0,e1,e2,e3,e4,e5,e6,e7;
    #define DOT(qi, ei) { \
        float d = act ? (qi.x*v4.x + qi.y*v4.y + qi.z*v4.z + qi.w*v4.w) : 0.f; \
        ei = wave_sum(d); }
    DOT(q0,e0) DOT(q1,e1) DOT(q2,e2) DOT(q3,e3)
    DOT(q4,e4) DOT(q5,e5) DOT(q6,e6) DOT(q7,e7)
    #undef DOT

    // lanes 0..7 each own one row: p = exp(e) as double via 2^n * 2^r
    float e = e0;
    e = (lane == 1) ? e1 : e;  e = (lane == 2) ? e2 : e;
    e = (lane == 3) ? e3 : e;  e = (lane == 4) ? e4 : e;
    e = (lane == 5) ? e5 : e;  e = (lane == 6) ? e6 : e;
    e = (lane == 7) ? e7 : e;
    double ps = 0.0;
    if (lane < 8) {
        const float f = e * 1.4426950408889634f;   // e * log2(e)
        const float n = rintf(f);
        const float m = exp2f(f - n);              // v_exp_f32
        const long long eb = ((long long)(1023 + (int)n)) << 52;
        ps = (double)m * __longlong_as_double(eb);
    }
    // sum over the 8-lane group
    double p = ps;
    p += __shfl_xor(p, 1, 64);
    p += __shfl_xor(p, 2, 64);
    p += __shfl_xor(p, 4, 64);
    if (lane == 0) s_lds[wid] = p;
    __syncthreads();

    if (t == 0) {
        const double S = s_lds[0] + s_lds[1] + s_lds[2] + s_lds[3];
        unsafeAtomicAdd((double*)(ws + WS_SUBT(b & 7)), S);
        __threadfence();   // the add is complete+visible before arrival
        if (atomicAdd(&ws[WS_SUB2(b & 7)], 1ull) == (unsigned long long)(K2B/8 - 1)) {
            if (atomicAdd(&ws[WS_ROOT2], 1ull) == 7ull) {
                double T = 0.0;
                #pragma unroll
                for (int i = 0; i < 8; ++i)
                    T += __hip_atomic_load((double*)(ws + WS_SUBT(i)),
                                           __ATOMIC_RELAXED, __HIP_MEMORY_SCOPE_AGENT);
                const unsigned long long bits = (unsigned long long)__double_as_longlong(T);
                #pragma unroll
                for (int i = 0; i < 8; ++i)
                    __hip_atomic_store(&ws[WS_GO2(i)], bits, __ATOMIC_RELEASE,
                                       __HIP_MEMORY_SCOPE_AGENT);
            }
        }
    }
    if (t == 0) {   // read-only acquire polling (NO RMW)
        unsigned long long g;
        while ((g = __hip_atomic_load(&ws[WS_GO2(b & 7)], __ATOMIC_ACQUIRE,
                                      __HIP_MEMORY_SCOPE_AGENT)) == 0ull)
            __builtin_amdgcn_s_sleep(8);
        inv_lds = 1.0 / __longlong_as_double((long long)g);
    }
    __syncthreads();
    const double inv = inv_lds;
    if (lane < 8)
        out[s0 + lane] = (float)(ps * inv);
}

extern "C" void kernel_launch(void* const* d_in, const int* in_sizes, int n_in,
                              void* d_out, int out_size, void* d_ws, size_t ws_size,
                              hipStream_t stream) {
    const float* hidden = (const float*)d_in[0];   // [H]
    const float* enc    = (const float*)d_in[1];   // [SEQ, DENC]
    const float* W      = (const float*)d_in[2];   // [H, 200]
    float* out = (float*)d_out;
    unsigned long long* ws = (unsigned long long*)d_ws;

    hipMemsetAsync(d_ws, 0, WS_ZERO_BYTES, stream);
    k1_proj<<<K1B, 256, 0, stream>>>(W, hidden, ws);
    k2_attn<<<K2B, 256, 0, stream>>>(enc, ws, out);
}

// Round 6
// 21.095 us; speedup vs baseline: 4.8018x; 4.8018x over previous
//
#include <hip/hip_runtime.h>
#include <math.h>

#define SEQ   32768
#define DENC  200
#define NH    8192

#define K1B       128
#define K1T       512
#define K1ROWS_PB (NH / K1B)             // 64 rows per block
#define K1ROWS_PG (K1ROWS_PB / 2)        // 32 rows per 256-thread group

#define K2B    1024
#define K2ROWS (SEQ / K2B)               // 32 rows per block
#define RPW    8                         // rows per wave

#define K3B    (SEQ / 256)               // 128

// ws layout: double ws_p[SEQ]; double ws_sum[K2B]; float ws_v[K1B*DENC]
// (everything fully rewritten every launch; no zeroing needed, no atomics)

__device__ __forceinline__ double wave_sum_d(double x) {
    #pragma unroll
    for (int off = 32; off; off >>= 1) x += __shfl_xor(x, off, 64);
    return x;
}
__device__ __forceinline__ float wave_sum(float x) {
    #pragma unroll
    for (int off = 32; off; off >>= 1) x += __shfl_xor(x, off, 64);
    return x;
}

// ---- K1: 128 v-partials. Coalesced W read (row = 800B, threads cover cols).
__global__ __launch_bounds__(K1T) void k1_proj(const float* __restrict__ W,
                                               const float* __restrict__ hidden,
                                               float* __restrict__ ws_v) {
    __shared__ float part[2][DENC];
    const int t = threadIdx.x, b = blockIdx.x;
    const int g = t >> 8, lt = t & 255;
    const int h0 = b * K1ROWS_PB + g * K1ROWS_PG;

    if (lt < DENC) {
        float acc = 0.f;
        #pragma unroll 8
        for (int i = 0; i < K1ROWS_PG; ++i)
            acc = fmaf(W[(size_t)(h0 + i) * DENC + lt], hidden[h0 + i], acc);
        part[g][lt] = acc;
    }
    __syncthreads();
    if (t < DENC)
        ws_v[b * DENC + t] = part[0][t] + part[1][t];   // [p][d], coalesced
}

// ---- K2: energies from register-preloaded enc rows; exp via v_exp_f32 +
// exponent-bit double scale (no max pass; |e|max ~ 240 << 709).
__global__ __launch_bounds__(256, 4) void k2_energy(const float* __restrict__ enc,
                                                    const float* __restrict__ ws_v,
                                                    double* __restrict__ ws_p,
                                                    double* __restrict__ ws_sum) {
    __shared__ float  v_lds[DENC];
    __shared__ double s_lds[4];
    const int t = threadIdx.x, b = blockIdx.x;
    const int lane = t & 63, wid = t >> 6;
    const bool act = (lane < 50);

    // issue all enc loads first; v-reduce below overlaps their latency
    const int s0 = b * K2ROWS + wid * RPW;
    const float* ebase = enc + (size_t)s0 * DENC + lane * 4;
    float4 q0 = *(const float4*)(act ? ebase + 0*DENC : enc);
    float4 q1 = *(const float4*)(act ? ebase + 1*DENC : enc);
    float4 q2 = *(const float4*)(act ? ebase + 2*DENC : enc);
    float4 q3 = *(const float4*)(act ? ebase + 3*DENC : enc);
    float4 q4 = *(const float4*)(act ? ebase + 4*DENC : enc);
    float4 q5 = *(const float4*)(act ? ebase + 5*DENC : enc);
    float4 q6 = *(const float4*)(act ? ebase + 6*DENC : enc);
    float4 q7 = *(const float4*)(act ? ebase + 7*DENC : enc);

    // redundant per-block v-reduce: 100KB, L2-resident, coalesced
    if (t < DENC) {
        float a0 = 0.f, a1 = 0.f, a2 = 0.f, a3 = 0.f;
        const float* p = ws_v + t;
        #pragma unroll 8
        for (int i = 0; i < K1B; i += 4) {
            a0 += p[(size_t)(i + 0) * DENC];
            a1 += p[(size_t)(i + 1) * DENC];
            a2 += p[(size_t)(i + 2) * DENC];
            a3 += p[(size_t)(i + 3) * DENC];
        }
        v_lds[t] = (a0 + a1) + (a2 + a3);
    }
    __syncthreads();

    float4 v4 = make_float4(0.f, 0.f, 0.f, 0.f);
    if (act) v4 = *(const float4*)(v_lds + lane * 4);

    float e0,e1,e2,e3,e4,e5,e6,e7;
    #define DOT(qi, ei) { \
        float d = act ? (qi.x*v4.x + qi.y*v4.y + qi.z*v4.z + qi.w*v4.w) : 0.f; \
        ei = wave_sum(d); }
    DOT(q0,e0) DOT(q1,e1) DOT(q2,e2) DOT(q3,e3)
    DOT(q4,e4) DOT(q5,e5) DOT(q6,e6) DOT(q7,e7)
    #undef DOT

    // lanes 0..7 own rows s0..s0+7
    float e = e0;
    e = (lane == 1) ? e1 : e;  e = (lane == 2) ? e2 : e;
    e = (lane == 3) ? e3 : e;  e = (lane == 4) ? e4 : e;
    e = (lane == 5) ? e5 : e;  e = (lane == 6) ? e6 : e;
    e = (lane == 7) ? e7 : e;
    double ps = 0.0;
    if (lane < 8) {
        const float f = e * 1.4426950408889634f;   // e / ln(2)
        const float n = rintf(f);
        const float m = exp2f(f - n);              // v_exp_f32
        const long long eb = ((long long)(1023 + (int)n)) << 52;
        ps = (double)m * __longlong_as_double(eb); // exact 2^n scale
        ws_p[s0 + lane] = ps;                      // 64B/wave contiguous
    }
    double p = ps;                                 // sum the 8-lane group
    p += __shfl_xor(p, 1, 64);
    p += __shfl_xor(p, 2, 64);
    p += __shfl_xor(p, 4, 64);
    if (lane == 0) s_lds[wid] = p;
    __syncthreads();
    if (t == 0) ws_sum[b] = (s_lds[0] + s_lds[1]) + (s_lds[2] + s_lds[3]);
}

// ---- K3: redundant global-sum reduce (8KB, L2), normalize, write out.
__global__ __launch_bounds__(256) void k3_norm(const double* __restrict__ ws_p,
                                               const double* __restrict__ ws_sum,
                                               float* __restrict__ out) {
    __shared__ double s_lds[4];
    __shared__ double inv_lds;
    const int t = threadIdx.x, b = blockIdx.x;
    const int lane = t & 63, wid = t >> 6;

    double a = (ws_sum[t] + ws_sum[t + 256]) + (ws_sum[t + 512] + ws_sum[t + 768]);
    a = wave_sum_d(a);
    if (lane == 0) s_lds[wid] = a;
    __syncthreads();
    if (t == 0) inv_lds = 1.0 / ((s_lds[0] + s_lds[1]) + (s_lds[2] + s_lds[3]));
    __syncthreads();

    const int i = b * 256 + t;
    out[i] = (float)(ws_p[i] * inv_lds);
}

extern "C" void kernel_launch(void* const* d_in, const int* in_sizes, int n_in,
                              void* d_out, int out_size, void* d_ws, size_t ws_size,
                              hipStream_t stream) {
    const float* hidden = (const float*)d_in[0];   // [H]
    const float* enc    = (const float*)d_in[1];   // [SEQ, DENC]
    const float* W      = (const float*)d_in[2];   // [H, 200]
    float* out = (float*)d_out;

    double* ws_p   = (double*)d_ws;                // [SEQ]
    double* ws_sum = ws_p + SEQ;                   // [K2B]
    float*  ws_v   = (float*)(ws_sum + K2B);       // [K1B*DENC]

    k1_proj  <<<K1B, K1T, 0, stream>>>(W, hidden, ws_v);
    k2_energy<<<K2B, 256, 0, stream>>>(enc, ws_v, ws_p, ws_sum);
    k3_norm  <<<K3B, 256, 0, stream>>>(ws_p, ws_sum, out);
}

// Round 7
// 20.820 us; speedup vs baseline: 4.8653x; 1.0132x over previous
//
#include <hip/hip_runtime.h>
#include <math.h>

#define SEQ   32768
#define DENC  200
#define NH    8192

#define K1B       128
#define K1T       512
#define K1ROWS_PB (NH / K1B)             // 64 rows per block
#define K1ROWS_PG (K1ROWS_PB / 2)        // 32 rows per 256-thread group
#define NBANK     8

#define K2B    1024
#define K2ROWS (SEQ / K2B)               // 32 rows per block
#define RPW    8                         // rows per wave

#define K3B    (SEQ / 256)               // 128

// ws layout (doubles):
//   [0, NBANK*DENC)   vacc banks (zeroed each launch: 12.8 KB)
//   then ws_p[SEQ], ws_sum[K2B]
#define VACC_BYTES (NBANK * DENC * 8)

__device__ __forceinline__ double wave_sum_d(double x) {
    #pragma unroll
    for (int off = 32; off; off >>= 1) x += __shfl_xor(x, off, 64);
    return x;
}
__device__ __forceinline__ float wave_sum(float x) {
    #pragma unroll
    for (int off = 32; off; off >>= 1) x += __shfl_xor(x, off, 64);
    return x;
}

// ---- K1: v[d] += sum of this block's 64 W-rows, via f64 atomic banks.
__global__ __launch_bounds__(K1T) void k1_proj(const float* __restrict__ W,
                                               const float* __restrict__ hidden,
                                               double* __restrict__ vacc) {
    __shared__ float part[2][DENC];
    const int t = threadIdx.x, b = blockIdx.x;
    const int g = t >> 8, lt = t & 255;
    const int h0 = b * K1ROWS_PB + g * K1ROWS_PG;

    if (lt < DENC) {
        float acc = 0.f;
        #pragma unroll 8
        for (int i = 0; i < K1ROWS_PG; ++i)
            acc = fmaf(W[(size_t)(h0 + i) * DENC + lt], hidden[h0 + i], acc);
        part[g][lt] = acc;
    }
    __syncthreads();
    if (t < DENC)
        unsafeAtomicAdd(&vacc[(b & (NBANK - 1)) * DENC + t],
                        (double)(part[0][t] + part[1][t]));
}

// ---- K2: energies from register-preloaded enc rows; v from 8 tiny banks;
// exp via v_exp_f32 + exponent-bit double scale (no max pass; |e| << 709).
__global__ __launch_bounds__(256) void k2_energy(const float* __restrict__ enc,
                                                 const double* __restrict__ vacc,
                                                 double* __restrict__ ws_p,
                                                 double* __restrict__ ws_sum) {
    __shared__ float  v_lds[DENC];
    __shared__ double s_lds[4];
    const int t = threadIdx.x, b = blockIdx.x;
    const int lane = t & 63, wid = t >> 6;
    const bool act = (lane < 50);

    // enc loads first: they are the long pole
    const int s0 = b * K2ROWS + wid * RPW;
    const float* ebase = enc + (size_t)s0 * DENC + lane * 4;
    float4 q0 = *(const float4*)(act ? ebase + 0*DENC : enc);
    float4 q1 = *(const float4*)(act ? ebase + 1*DENC : enc);
    float4 q2 = *(const float4*)(act ? ebase + 2*DENC : enc);
    float4 q3 = *(const float4*)(act ? ebase + 3*DENC : enc);
    float4 q4 = *(const float4*)(act ? ebase + 4*DENC : enc);
    float4 q5 = *(const float4*)(act ? ebase + 5*DENC : enc);
    float4 q6 = *(const float4*)(act ? ebase + 6*DENC : enc);
    float4 q7 = *(const float4*)(act ? ebase + 7*DENC : enc);

    // v from banks: 12.8 KB per block
    if (t < DENC) {
        double a = 0.0;
        #pragma unroll
        for (int k = 0; k < NBANK; ++k) a += vacc[k * DENC + t];
        v_lds[t] = (float)a;
    }
    __syncthreads();

    float4 v4 = make_float4(0.f, 0.f, 0.f, 0.f);
    if (act) v4 = *(const float4*)(v_lds + lane * 4);

    float e0,e1,e2,e3,e4,e5,e6,e7;
    #define DOT(qi, ei) { \
        float d = act ? (qi.x*v4.x + qi.y*v4.y + qi.z*v4.z + qi.w*v4.w) : 0.f; \
        ei = wave_sum(d); }
    DOT(q0,e0) DOT(q1,e1) DOT(q2,e2) DOT(q3,e3)
    DOT(q4,e4) DOT(q5,e5) DOT(q6,e6) DOT(q7,e7)
    #undef DOT

    // lanes 0..7 own rows s0..s0+7
    float e = e0;
    e = (lane == 1) ? e1 : e;  e = (lane == 2) ? e2 : e;
    e = (lane == 3) ? e3 : e;  e = (lane == 4) ? e4 : e;
    e = (lane == 5) ? e5 : e;  e = (lane == 6) ? e6 : e;
    e = (lane == 7) ? e7 : e;
    double ps = 0.0;
    if (lane < 8) {
        const float f = e * 1.4426950408889634f;   // e / ln(2)
        const float n = rintf(f);
        const float m = exp2f(f - n);              // v_exp_f32
        const long long eb = ((long long)(1023 + (int)n)) << 52;
        ps = (double)m * __longlong_as_double(eb); // exact 2^n scale
        ws_p[s0 + lane] = ps;                      // contiguous 64B/wave
    }
    double p = ps;                                 // 8-lane group sum
    p += __shfl_xor(p, 1, 64);
    p += __shfl_xor(p, 2, 64);
    p += __shfl_xor(p, 4, 64);
    if (lane == 0) s_lds[wid] = p;
    __syncthreads();
    if (t == 0) ws_sum[b] = (s_lds[0] + s_lds[1]) + (s_lds[2] + s_lds[3]);
}

// ---- K3: redundant global-sum reduce (8KB, L2), normalize, write out.
__global__ __launch_bounds__(256) void k3_norm(const double* __restrict__ ws_p,
                                               const double* __restrict__ ws_sum,
                                               float* __restrict__ out) {
    __shared__ double s_lds[4];
    __shared__ double inv_lds;
    const int t = threadIdx.x, b = blockIdx.x;
    const int lane = t & 63, wid = t >> 6;

    double a = (ws_sum[t] + ws_sum[t + 256]) + (ws_sum[t + 512] + ws_sum[t + 768]);
    a = wave_sum_d(a);
    if (lane == 0) s_lds[wid] = a;
    __syncthreads();
    if (t == 0) inv_lds = 1.0 / ((s_lds[0] + s_lds[1]) + (s_lds[2] + s_lds[3]));
    __syncthreads();

    const int i = b * 256 + t;
    out[i] = (float)(ws_p[i] * inv_lds);
}

extern "C" void kernel_launch(void* const* d_in, const int* in_sizes, int n_in,
                              void* d_out, int out_size, void* d_ws, size_t ws_size,
                              hipStream_t stream) {
    const float* hidden = (const float*)d_in[0];   // [H]
    const float* enc    = (const float*)d_in[1];   // [SEQ, DENC]
    const float* W      = (const float*)d_in[2];   // [H, 200]
    float* out = (float*)d_out;

    double* vacc   = (double*)d_ws;                // [NBANK*DENC]
    double* ws_p   = vacc + NBANK * DENC;          // [SEQ]
    double* ws_sum = ws_p + SEQ;                   // [K2B]

    hipMemsetAsync(d_ws, 0, VACC_BYTES, stream);
    k1_proj  <<<K1B, K1T, 0, stream>>>(W, hidden, vacc);
    k2_energy<<<K2B, 256, 0, stream>>>(enc, vacc, ws_p, ws_sum);
    k3_norm  <<<K3B, 256, 0, stream>>>(ws_p, ws_sum, out);
}

// Round 8
// 19.235 us; speedup vs baseline: 5.2663x; 1.0824x over previous
//
#include <hip/hip_runtime.h>
#include <math.h>

#define SEQ   32768
#define DENC  200
#define NH    8192

#define K1B       64
#define K1T       1024
#define K1ROWS_PB (NH / K1B)             // 128 rows per block
#define K1ROWS_PG (K1ROWS_PB / 4)        // 32 rows per 256-thread group

#define K2B    512
#define K2T    512                       // 8 waves
#define K2ROWS (SEQ / K2B)               // 64 rows per block
#define RPW    8                         // rows per wave

#define K3B    (SEQ / 256)               // 128

// ws layout: float ws_v[K1B*DENC] (plain-stored banks); double ws_p[SEQ];
// double ws_sum[K2B]. Everything fully rewritten every launch; no zeroing.

__device__ __forceinline__ double wave_sum_d(double x) {
    #pragma unroll
    for (int off = 32; off; off >>= 1) x += __shfl_xor(x, off, 64);
    return x;
}
__device__ __forceinline__ float wave_sum(float x) {
    #pragma unroll
    for (int off = 32; off; off >>= 1) x += __shfl_xor(x, off, 64);
    return x;
}

// ---- K1: 64 plain-stored v-partial banks (no atomics, no memset).
__global__ __launch_bounds__(K1T) void k1_proj(const float* __restrict__ W,
                                               const float* __restrict__ hidden,
                                               float* __restrict__ ws_v) {
    __shared__ float part[4][DENC];
    const int t = threadIdx.x, b = blockIdx.x;
    const int g = t >> 8, lt = t & 255;
    const int h0 = b * K1ROWS_PB + g * K1ROWS_PG;

    if (lt < DENC) {
        float acc = 0.f;
        #pragma unroll 8
        for (int i = 0; i < K1ROWS_PG; ++i)
            acc = fmaf(W[(size_t)(h0 + i) * DENC + lt], hidden[h0 + i], acc);
        part[g][lt] = acc;
    }
    __syncthreads();
    if (t < DENC)
        ws_v[b * DENC + t] = (part[0][t] + part[1][t]) + (part[2][t] + part[3][t]);
}

// ---- K2: energies from register-preloaded enc rows; v reduced from 64 banks;
// exp via v_exp_f32 + exponent-bit double scale (no max pass; |e| << 709).
__global__ __launch_bounds__(K2T) void k2_energy(const float* __restrict__ enc,
                                                 const float* __restrict__ ws_v,
                                                 double* __restrict__ ws_p,
                                                 double* __restrict__ ws_sum) {
    __shared__ float  v_lds[DENC];
    __shared__ double s_lds[K2T / 64];
    const int t = threadIdx.x, b = blockIdx.x;
    const int lane = t & 63, wid = t >> 6;
    const bool act = (lane < 50);

    // enc loads first: they are the long pole
    const int s0 = b * K2ROWS + wid * RPW;
    const float* ebase = enc + (size_t)s0 * DENC + lane * 4;
    float4 q0 = *(const float4*)(act ? ebase + 0*DENC : enc);
    float4 q1 = *(const float4*)(act ? ebase + 1*DENC : enc);
    float4 q2 = *(const float4*)(act ? ebase + 2*DENC : enc);
    float4 q3 = *(const float4*)(act ? ebase + 3*DENC : enc);
    float4 q4 = *(const float4*)(act ? ebase + 4*DENC : enc);
    float4 q5 = *(const float4*)(act ? ebase + 5*DENC : enc);
    float4 q6 = *(const float4*)(act ? ebase + 6*DENC : enc);
    float4 q7 = *(const float4*)(act ? ebase + 7*DENC : enc);

    // v from 64 float banks: 51.2 KB per block, L2-resident, coalesced
    if (t < DENC) {
        float a0 = 0.f, a1 = 0.f, a2 = 0.f, a3 = 0.f;
        const float* p = ws_v + t;
        #pragma unroll 4
        for (int k = 0; k < K1B; k += 4) {
            a0 += p[(size_t)(k + 0) * DENC];
            a1 += p[(size_t)(k + 1) * DENC];
            a2 += p[(size_t)(k + 2) * DENC];
            a3 += p[(size_t)(k + 3) * DENC];
        }
        v_lds[t] = (a0 + a1) + (a2 + a3);
    }
    __syncthreads();

    float4 v4 = make_float4(0.f, 0.f, 0.f, 0.f);
    if (act) v4 = *(const float4*)(v_lds + lane * 4);

    float e0,e1,e2,e3,e4,e5,e6,e7;
    #define DOT(qi, ei) { \
        float d = act ? (qi.x*v4.x + qi.y*v4.y + qi.z*v4.z + qi.w*v4.w) : 0.f; \
        ei = wave_sum(d); }
    DOT(q0,e0) DOT(q1,e1) DOT(q2,e2) DOT(q3,e3)
    DOT(q4,e4) DOT(q5,e5) DOT(q6,e6) DOT(q7,e7)
    #undef DOT

    // lanes 0..7 own rows s0..s0+7
    float e = e0;
    e = (lane == 1) ? e1 : e;  e = (lane == 2) ? e2 : e;
    e = (lane == 3) ? e3 : e;  e = (lane == 4) ? e4 : e;
    e = (lane == 5) ? e5 : e;  e = (lane == 6) ? e6 : e;
    e = (lane == 7) ? e7 : e;
    double ps = 0.0;
    if (lane < 8) {
        const float f = e * 1.4426950408889634f;   // e / ln(2)
        const float n = rintf(f);
        const float m = exp2f(f - n);              // v_exp_f32
        const long long eb = ((long long)(1023 + (int)n)) << 52;
        ps = (double)m * __longlong_as_double(eb); // exact 2^n scale
        ws_p[s0 + lane] = ps;                      // contiguous 64B/wave
    }
    double p = ps;                                 // 8-lane group sum
    p += __shfl_xor(p, 1, 64);
    p += __shfl_xor(p, 2, 64);
    p += __shfl_xor(p, 4, 64);
    if (lane == 0) s_lds[wid] = p;
    __syncthreads();
    if (t == 0) {
        double S = 0.0;
        #pragma unroll
        for (int w = 0; w < K2T / 64; ++w) S += s_lds[w];
        ws_sum[b] = S;
    }
}

// ---- K3: redundant global-sum reduce (4KB, L2), normalize, write out.
__global__ __launch_bounds__(256) void k3_norm(const double* __restrict__ ws_p,
                                               const double* __restrict__ ws_sum,
                                               float* __restrict__ out) {
    __shared__ double s_lds[4];
    __shared__ double inv_lds;
    const int t = threadIdx.x, b = blockIdx.x;
    const int lane = t & 63, wid = t >> 6;

    double a = ws_sum[t] + ws_sum[t + 256];        // K2B=512 -> 2 per thread
    a = wave_sum_d(a);
    if (lane == 0) s_lds[wid] = a;
    __syncthreads();
    if (t == 0) inv_lds = 1.0 / ((s_lds[0] + s_lds[1]) + (s_lds[2] + s_lds[3]));
    __syncthreads();

    const int i = b * 256 + t;
    out[i] = (float)(ws_p[i] * inv_lds);
}

extern "C" void kernel_launch(void* const* d_in, const int* in_sizes, int n_in,
                              void* d_out, int out_size, void* d_ws, size_t ws_size,
                              hipStream_t stream) {
    const float* hidden = (const float*)d_in[0];   // [H]
    const float* enc    = (const float*)d_in[1];   // [SEQ, DENC]
    const float* W      = (const float*)d_in[2];   // [H, 200]
    float* out = (float*)d_out;

    float*  ws_v   = (float*)d_ws;                 // [K1B*DENC]
    double* ws_p   = (double*)(ws_v + K1B * DENC); // [SEQ]
    double* ws_sum = ws_p + SEQ;                   // [K2B]

    k1_proj  <<<K1B, K1T, 0, stream>>>(W, hidden, ws_v);
    k2_energy<<<K2B, K2T, 0, stream>>>(enc, ws_v, ws_p, ws_sum);
    k3_norm  <<<K3B, 256, 0, stream>>>(ws_p, ws_sum, out);
}